// Round 22
// baseline (708.777 us; speedup 1.0000x reference)
//
#include <hip/hip_runtime.h>
#include <math.h>

// ---------------------------------------------------------------------------
// conv1 + prep_w fused (both independent, both must precede conv2).
__global__ void k_conv1p(const float* __restrict__ x, const float* __restrict__ w1,
                         const float* __restrict__ b1, float* __restrict__ a1,
                         const float* __restrict__ w2, float* __restrict__ w2t,
                         const float* __restrict__ w3, float* __restrict__ w3t) {
  if (blockIdx.x < 32768) {
    int idx = blockIdx.x * 256 + threadIdx.x;
    int ox = idx & 31, oy = (idx >> 5) & 31, oc = (idx >> 10) & 15, n = idx >> 14;
    const float* im = x + n * 4096;
    float wv[9];
#pragma unroll
    for (int i = 0; i < 9; ++i) wv[i] = w1[oc * 9 + i];
    float bs = b1[oc];
    float m = 0.f;
#pragma unroll
    for (int dy = 0; dy < 2; ++dy)
#pragma unroll
      for (int dx = 0; dx < 2; ++dx) {
        int cy = oy * 2 + dy, cx = ox * 2 + dx;
        float s = bs;
#pragma unroll
        for (int ky = 0; ky < 3; ++ky) {
          int yy = cy + ky - 1;
          if (yy < 0 || yy >= 64) continue;
#pragma unroll
          for (int kx = 0; kx < 3; ++kx) {
            int xx = cx + kx - 1;
            if (xx < 0 || xx >= 64) continue;
            s += im[yy * 64 + xx] * wv[ky * 3 + kx];
          }
        }
        m = fmaxf(m, fmaxf(s, 0.f));
      }
    a1[idx] = m;
  } else {
    int id = (blockIdx.x - 32768) * 256 + threadIdx.x;
    if (id < 73728) {
      int ct = id >> 8, oc = id & 255;
      int c = ct / 9, tap = ct - 9 * c;
      w3t[id] = w3[(oc * 32 + c) * 9 + tap];
    }
    if (id < 4608) {
      int ct = id >> 5, oc = id & 31;
      int c = ct / 9, tap = ct - 9 * c;
      w2t[id] = w2[(oc * 16 + c) * 9 + tap];
    }
  }
}

// ---------------------------------------------------------------------------
// conv2: a1[512][16][32][32] -> relu -> maxpool2 -> a2[n][px=256][oc=32]
__global__ __launch_bounds__(256) void k_conv2(
    const float* __restrict__ a1, const float* __restrict__ w2t,
    const float* __restrict__ bias, float* __restrict__ a2) {
  __shared__ __align__(16) float ins[8 * 1024];
  int n = blockIdx.x, ocg = blockIdx.y;
  int tid = threadIdx.x;
  int py = tid >> 4, px = tid & 15;
  int y0 = 2 * py - 1, x0 = 2 * px - 1;
  float acc[16][4] = {};
  const float* wb = w2t + ocg * 16;
  for (int ph = 0; ph < 2; ++ph) {
    __syncthreads();
    const float4* src = (const float4*)(a1 + n * 16384 + ph * 8192);
    for (int i = tid; i < 2048; i += 256) ((float4*)ins)[i] = src[i];
    __syncthreads();
    for (int c = 0; c < 8; ++c) {
      float wv[4][4];
#pragma unroll
      for (int r = 0; r < 4; ++r) {
        int y = y0 + r;
        bool vy = (y >= 0) && (y < 32);
        int yc = vy ? y : 0;
#pragma unroll
        for (int cc = 0; cc < 4; ++cc) {
          int xx = x0 + cc;
          bool vx = (xx >= 0) && (xx < 32);
          int xc = vx ? xx : 0;
          float t = ins[c * 1024 + yc * 32 + xc];
          wv[r][cc] = (vy && vx) ? t : 0.f;
        }
      }
      int ch = ph * 8 + c;
#pragma unroll
      for (int ky = 0; ky < 3; ++ky)
#pragma unroll
        for (int kx = 0; kx < 3; ++kx) {
          const float* w16 = wb + (ch * 9 + ky * 3 + kx) * 32;
#pragma unroll
          for (int i = 0; i < 4; ++i) {
            float vv = wv[(i >> 1) + ky][(i & 1) + kx];
#pragma unroll
            for (int j = 0; j < 16; ++j) acc[j][i] += vv * w16[j];
          }
        }
    }
  }
  const float* bp = bias + ocg * 16;
  float4 o[4];
#pragma unroll
  for (int j = 0; j < 16; ++j) {
    float m = fmaxf(fmaxf(acc[j][0], acc[j][1]), fmaxf(acc[j][2], acc[j][3]));
    ((float*)o)[j] = fmaxf(m + bp[j], 0.f);
  }
  float4* dst = (float4*)(a2 + (size_t)(n * 256 + tid) * 32 + ocg * 16);
#pragma unroll
  for (int q = 0; q < 4; ++q) dst[q] = o[q];
}

// ---------------------------------------------------------------------------
// conv3 v7 body (best measured; v3/v7 = measured local optimum)
__device__ __forceinline__ void conv3_body(
    int n, int ocb, int tid, const float* __restrict__ a2,
    const float* __restrict__ w3t, const float* __restrict__ bias,
    float* __restrict__ comb0, float* __restrict__ ins /* >=3240 f */) {
  float2* ins2 = (float2*)ins;
  for (int i = tid; i < 810; i += 256) ((float4*)ins)[i] = float4{0.f, 0.f, 0.f, 0.f};
  int wvid = __builtin_amdgcn_readfirstlane(tid >> 6);
  int lane = tid & 63;
  int tr = lane >> 4, tc = lane & 15;
  float acc[4][8] = {};
  const float* wbase = w3t + ocb * 32 + wvid * 8;
  const float4* src = (const float4*)(a2 + (size_t)n * 8192);
  for (int ph = 0; ph < 4; ++ph) {
    __syncthreads();
    for (int i = tid; i < 512; i += 256) {
      int px = i >> 1, cgl = i & 1;
      int p = ((px >> 4) + 1) * 18 + (px & 15) + 1;
      float4 v = src[px * 8 + ph * 2 + cgl];
      ins2[p * 5 + cgl * 2]     = float2{v.x, v.y};
      ins2[p * 5 + cgl * 2 + 1] = float2{v.z, v.w};
    }
    __syncthreads();
    for (int cg2 = 0; cg2 < 4; ++cg2) {
      float2 v[6][3];
#pragma unroll
      for (int dr = 0; dr < 6; ++dr)
#pragma unroll
        for (int dc = 0; dc < 3; ++dc)
          v[dr][dc] = ins2[((4 * tr + dr) * 18 + tc + dc) * 5 + cg2];
#pragma unroll
      for (int ky = 0; ky < 3; ++ky)
#pragma unroll
        for (int kx = 0; kx < 3; ++kx)
#pragma unroll
          for (int c = 0; c < 2; ++c) {
            const float* w8 =
                wbase + ((ph * 8 + cg2 * 2 + c) * 9 + ky * 3 + kx) * 256;
#pragma unroll
            for (int i = 0; i < 4; ++i) {
              float vv = c ? v[i + ky][kx].y : v[i + ky][kx].x;
#pragma unroll
              for (int j = 0; j < 8; ++j) acc[i][j] += vv * w8[j];
            }
          }
    }
  }
  const float* bp = bias + ocb * 32 + wvid * 8;
  int bb = n >> 4, tt = n & 15;
#pragma unroll
  for (int j = 0; j < 8; ++j) {
    float bj = bp[j];
    float s = 0.f;
#pragma unroll
    for (int i = 0; i < 4; ++i) s += fmaxf(acc[i][j] + bj, 0.f);
#pragma unroll
    for (int off = 32; off; off >>= 1) s += __shfl_down(s, off, 64);
    if (lane == 0) {
      int oc = ocb * 32 + wvid * 8 + j;
      comb0[(size_t)(tt * 768 + oc) * 32 + bb] = s * (1.f / 256.f);
    }
  }
}

// ---------------------------------------------------------------------------
// pack body: p[h][k][4] = (Wf[k][h], Wi[k][h], Wg[k][h], Wo[k][h])
__device__ __forceinline__ void pack_body(
    const float* __restrict__ Wf, const float* __restrict__ Wi,
    const float* __restrict__ Wg, const float* __restrict__ Wo,
    float* __restrict__ p, int fan, int k0, int h0, int tid,
    float* __restrict__ t) {  // t = [4][32][33] floats
  int tx = tid & 31, ty = tid >> 5;  // 32 x 8
  const float* Ws[4] = {Wf, Wi, Wg, Wo};
#pragma unroll
  for (int g = 0; g < 4; ++g)
    for (int r = 0; r < 32; r += 8)
      t[(g * 32 + ty + r) * 33 + tx] =
          Ws[g][(size_t)(k0 + ty + r) * 512 + h0 + tx];
  __syncthreads();
  for (int r = 0; r < 32; r += 8) {
    int hh = ty + r;
    float4 v = {t[(0 * 32 + tx) * 33 + hh], t[(1 * 32 + tx) * 33 + hh],
                t[(2 * 32 + tx) * 33 + hh], t[(3 * 32 + tx) * 33 + hh]};
    ((float4*)p)[(size_t)(h0 + hh) * fan + k0 + tx] = v;
  }
}

// ---------------------------------------------------------------------------
// conv3 + pack(p0,p1) + zero fused: all three depend only on conv2 being
// done and are mutually independent (prep writes region0 = dead a1 + the
// comb h-parts; conv3 writes comb emb-parts). One launch; prep's ~5us hides
// under conv3's ~200us. Blocks: [0,4096) conv3 (ocb=bid>>9, n=bid&511 --
// preserves the old 2D launch's n-fastest ordering); [4096,4480) pack p0;
// [4480,4992) pack p1; [4992,5120) zero.
struct C3PArgs {
  const float* a2; const float* w3t; const float* b3; float* comb0;
  const float* l00; const float* l01; const float* l02; const float* l03;
  const float* l10; const float* l11; const float* l12; const float* l13;
  float* p0; float* p1;
  float* c0h; float* c1h; float* cc; int* bar;
};

__global__ __launch_bounds__(256) void k_c3p(C3PArgs P) {
  __shared__ __align__(16) float sh[4224];  // max(conv3 3240f, pack 4224f)
  int bid = blockIdx.x, tid = threadIdx.x;
  if (bid < 4096) {
    conv3_body(bid & 511, bid >> 9, tid, P.a2, P.w3t, P.b3, P.comb0, sh);
  } else if (bid < 4480) {
    int b2 = bid - 4096;
    pack_body(P.l00, P.l01, P.l02, P.l03, P.p0, 768,
              (b2 % 24) * 32, (b2 / 24) * 32, tid, sh);
  } else if (bid < 4992) {
    int b2 = bid - 4480;
    pack_body(P.l10, P.l11, P.l12, P.l13, P.p1, 1024,
              (b2 % 32) * 32, (b2 / 32) * 32, tid, sh);
  } else {
    int i = (bid - 4992) * 256 + tid;  // [0, 32768)
    if (i < 16384) { P.c0h[i] = 0.f; P.c1h[i] = 0.f; }
    P.cc[i] = 0.f;
    if (i < 512) P.bar[i] = 0;
  }
}

// ---------------------------------------------------------------------------
// Persistent cooperative LSTM v15 + parallel classifier tail (round-20/21
// passing, ~233us). Hot MAC loops byte-identical.
struct Coop2Args {
  float* comb0; float* comb1;
  const float* p0; const float* p1;   // packed [512][FAN][4]
  const float* b00; const float* b01; const float* b02; const float* b03;
  const float* b10; const float* b11; const float* b12; const float* b13;
  int* bar;   // [512] ints: root @0; group g counter @ 32+g*32
  const float* cw1; const float* cb1; const float* cw2; const float* cb2;
  const float* cw3; const float* cb3; float* out;
};

// LDS floats: wl0 [0,6144) | wl1 [6144,14336) | gsum [14336,31488) |
// pre0 [31488,32000) | pre1 [32000,32512)  => 130,048 B (1 blk/CU)
#define COOP2_LDS_BYTES (32512 * 4)

#define FMA4(acc, s, a)                                   \
  acc.x += (s) * (a).x; acc.y += (s) * (a).y;             \
  acc.z += (s) * (a).z; acc.w += (s) * (a).w;

template <bool DO0, bool DO1>
__device__ __forceinline__ void fused_step(
    int hbase, int tid, int it, const Coop2Args& A,
    const float4* __restrict__ w40, const float4* __restrict__ w41,
    float* __restrict__ gsum, float* __restrict__ pre0,
    float* __restrict__ pre1,
    float bf0, float bi0, float bg0, float bo0,
    float bf1, float bi1, float bg1, float bo1,
    float& c0reg, float& c1reg) {
  const int C0 = 768 * 32, C1 = 1024 * 32;
  const int kc = tid >> 3, bq = tid & 7;
  float4 p0f{0,0,0,0}, p0i{0,0,0,0}, p0g{0,0,0,0}, p0o{0,0,0,0};
  float4 p1f{0,0,0,0}, p1i{0,0,0,0}, p1g{0,0,0,0}, p1o{0,0,0,0};
  float4 q0f{0,0,0,0}, q0i{0,0,0,0}, q0g{0,0,0,0}, q0o{0,0,0,0};
  float4 q1f{0,0,0,0}, q1i{0,0,0,0}, q1g{0,0,0,0}, q1o{0,0,0,0};
  if constexpr (DO1) {
    const float4* a41 = (const float4*)(A.comb1 + (size_t)(it - 1) * C1)
                        + kc * 8 + bq;
#pragma unroll
    for (int kk = 0; kk < 16; ++kk) {
      float4 a = a41[kk * 512];
      float4 u = w41[kk * 64];           // hs0 gates f,i,g,o for k=kk*64+kc
      float4 v = w41[1024 + kk * 64];    // hs1
      FMA4(q0f, u.x, a) FMA4(q0i, u.y, a) FMA4(q0g, u.z, a) FMA4(q0o, u.w, a)
      FMA4(q1f, v.x, a) FMA4(q1i, v.y, a) FMA4(q1g, v.z, a) FMA4(q1o, v.w, a)
    }
  }
  if constexpr (DO0) {
    const float4* a40 = (const float4*)(A.comb0 + (size_t)it * C0)
                        + kc * 8 + bq;
#pragma unroll
    for (int kk = 0; kk < 12; ++kk) {
      float4 a = a40[kk * 512];
      float4 u = w40[kk * 64];
      float4 v = w40[768 + kk * 64];
      FMA4(p0f, u.x, a) FMA4(p0i, u.y, a) FMA4(p0g, u.z, a) FMA4(p0o, u.w, a)
      FMA4(p1f, v.x, a) FMA4(p1i, v.y, a) FMA4(p1g, v.z, a) FMA4(p1o, v.w, a)
    }
  }
#define GW(hsv, gv, acc) {                                            \
    float* _r = gsum + (size_t)(((hsv) * 4 + (gv)) * 32 + 4 * bq) * 67 + kc; \
    _r[0] = acc.x; _r[67] = acc.y; _r[134] = acc.z; _r[201] = acc.w; }
  __syncthreads();   // previous consumers of gsum/pre done
  if constexpr (DO0) {
    GW(0, 0, p0f) GW(0, 1, p0i) GW(0, 2, p0g) GW(0, 3, p0o)
    GW(1, 0, p1f) GW(1, 1, p1i) GW(1, 2, p1g) GW(1, 3, p1o)
  }
  __syncthreads();
  if constexpr (DO0) {
    int row = tid & 255, half = tid >> 8;
    const float* gp = gsum + (size_t)row * 67 + half * 32;
    float s = 0.f;
#pragma unroll
    for (int q = 0; q < 32; ++q) s += gp[q];
    pre0[half * 256 + row] = s;
  }
  __syncthreads();   // gsum reads done -> reuse for l1
  if constexpr (DO1) {
    GW(0, 0, q0f) GW(0, 1, q0i) GW(0, 2, q0g) GW(0, 3, q0o)
    GW(1, 0, q1f) GW(1, 1, q1i) GW(1, 2, q1g) GW(1, 3, q1o)
  }
  __syncthreads();
  if constexpr (DO1) {
    int row = tid & 255, half = tid >> 8;
    const float* gp = gsum + (size_t)row * 67 + half * 32;
    float s = 0.f;
#pragma unroll
    for (int q = 0; q < 32; ++q) s += gp[q];
    pre1[half * 256 + row] = s;
  }
  __syncthreads();
#undef GW
  if (tid < 64) {
    int hs2 = tid >> 5, b = tid & 31, hh = hbase + hs2;
    int r = hs2 * 128 + b;
    if constexpr (DO0) {
      float fp = pre0[r] + pre0[256 + r] + bf0;
      float ip = pre0[r + 32] + pre0[256 + r + 32] + bi0;
      float gp = pre0[r + 64] + pre0[256 + r + 64] + bg0;
      float op = pre0[r + 96] + pre0[256 + r + 96] + bo0;
      float ft = 1.f / (1.f + expf(-fp));
      float it_ = 1.f / (1.f + expf(-ip));
      float gt = tanhf(gp);
      float ot = 1.f / (1.f + expf(-op));
      float cn = ft * c0reg + it_ * gt;
      c0reg = cn;
      float hn = ot * tanhf(cn);
      float* hA = A.comb0 + (size_t)(it + 1) * C0 + 256 * 32;
      float* hB = A.comb1 + (size_t)it * C1;
      __hip_atomic_store(&hA[hh * 32 + b], hn, __ATOMIC_RELAXED,
                         __HIP_MEMORY_SCOPE_AGENT);
      __hip_atomic_store(&hB[hh * 32 + b], hn, __ATOMIC_RELAXED,
                         __HIP_MEMORY_SCOPE_AGENT);
    }
    if constexpr (DO1) {
      float fp = pre1[r] + pre1[256 + r] + bf1;
      float ip = pre1[r + 32] + pre1[256 + r + 32] + bi1;
      float gp = pre1[r + 64] + pre1[256 + r + 64] + bg1;
      float op = pre1[r + 96] + pre1[256 + r + 96] + bo1;
      float ft = 1.f / (1.f + expf(-fp));
      float it_ = 1.f / (1.f + expf(-ip));
      float gt = tanhf(gp);
      float ot = 1.f / (1.f + expf(-op));
      float cn = ft * c1reg + it_ * gt;
      c1reg = cn;
      float hn = ot * tanhf(cn);
      float* hA = A.comb1 + (size_t)it * C1 + 512 * 32;
      __hip_atomic_store(&hA[hh * 32 + b], hn, __ATOMIC_RELAXED,
                         __HIP_MEMORY_SCOPE_AGENT);
    }
  }
}

// tree barrier: 8 group counters on separate lines (32 arrivals, ACQ_REL) +
// root (8 arrivals, RELEASE); poll root RELAXED + one ACQUIRE agent fence.
__device__ __forceinline__ void coop_barrier(int* bars, int tid, int bid,
                                             int it) {
  __syncthreads();
  if (tid == 0) {
    int* gb = bars + 32 + (bid & 7) * 32;
    int old = __hip_atomic_fetch_add(gb, 1, __ATOMIC_ACQ_REL,
                                     __HIP_MEMORY_SCOPE_AGENT);
    if (old == 32 * (it + 1) - 1)
      __hip_atomic_fetch_add(bars, 1, __ATOMIC_RELEASE,
                             __HIP_MEMORY_SCOPE_AGENT);
    while (__hip_atomic_load(bars, __ATOMIC_RELAXED,
                             __HIP_MEMORY_SCOPE_AGENT) < 8 * (it + 1))
      __builtin_amdgcn_s_sleep(2);
    __builtin_amdgcn_fence(__ATOMIC_ACQUIRE, "agent");
  }
  __syncthreads();
}

__global__ __launch_bounds__(512, 2) void k_lstm_coop2(Coop2Args A) {
  extern __shared__ float smem[];
  float* wl0 = smem;
  float* wl1 = smem + 6144;
  float* gsum = smem + 14336;
  float* pre0 = smem + 31488;
  float* pre1 = smem + 32000;
  const int tid = threadIdx.x;
  const int hbase = blockIdx.x * 2;
  // stage both layers' weights once
  for (int i = tid; i < 1536; i += 512) {
    int hs = (i >= 768), k = i - hs * 768;
    ((float4*)wl0)[hs * 768 + k] =
        ((const float4*)A.p0)[(size_t)(hbase + hs) * 768 + k];
  }
  for (int i = tid; i < 2048; i += 512) {
    int hs = i >> 10, k = i & 1023;
    ((float4*)wl1)[hs * 1024 + k] =
        ((const float4*)A.p1)[(size_t)(hbase + hs) * 1024 + k];
  }
  float bf0 = 0, bi0 = 0, bg0 = 0, bo0 = 0;
  float bf1 = 0, bi1 = 0, bg1 = 0, bo1 = 0;
  float c0reg = 0.f, c1reg = 0.f;
  if (tid < 64) {
    int hh = hbase + (tid >> 5);
    bf0 = A.b00[hh]; bi0 = A.b01[hh]; bg0 = A.b02[hh]; bo0 = A.b03[hh];
    bf1 = A.b10[hh]; bi1 = A.b11[hh]; bg1 = A.b12[hh]; bo1 = A.b13[hh];
  }
  __syncthreads();
  const int kc = tid >> 3;
  const float4* w40 = (const float4*)wl0 + kc;
  const float4* w41 = (const float4*)wl1 + kc;

  fused_step<true, false>(hbase, tid, 0, A, w40, w41, gsum, pre0, pre1,
                          bf0, bi0, bg0, bo0, bf1, bi1, bg1, bo1, c0reg, c1reg);
  coop_barrier(A.bar, tid, blockIdx.x, 0);
  for (int it = 1; it < 16; ++it) {
    fused_step<true, true>(hbase, tid, it, A, w40, w41, gsum, pre0, pre1,
                           bf0, bi0, bg0, bo0, bf1, bi1, bg1, bo1, c0reg, c1reg);
    coop_barrier(A.bar, tid, blockIdx.x, it);
  }
  fused_step<false, true>(hbase, tid, 16, A, w40, w41, gsum, pre0, pre1,
                          bf0, bi0, bg0, bo0, bf1, bi1, bg1, bo1, c0reg, c1reg);

  // final barrier: ALL blocks arrive; only cls blocks (0..31) poll.
  __syncthreads();
  if (tid == 0) {
    int* gb = A.bar + 32 + (blockIdx.x & 7) * 32;
    int old = __hip_atomic_fetch_add(gb, 1, __ATOMIC_ACQ_REL,
                                     __HIP_MEMORY_SCOPE_AGENT);
    if (old == 32 * 17 - 1)
      __hip_atomic_fetch_add(A.bar, 1, __ATOMIC_RELEASE,
                             __HIP_MEMORY_SCOPE_AGENT);
  }
  if (blockIdx.x < 32) {
    if (tid == 0) {
      while (__hip_atomic_load(A.bar, __ATOMIC_RELAXED,
                               __HIP_MEMORY_SCOPE_AGENT) < 8 * 17)
        __builtin_amdgcn_s_sleep(2);
      __builtin_amdgcn_fence(__ATOMIC_ACQUIRE, "agent");
    }
    __syncthreads();
    // parallel classifier for batch b = blockIdx.x (split-k via LDS)
    float* hv  = smem;           // 512   (wl0 region, dead)
    float* p1s = smem + 512;     // 4*128
    float* y1  = smem + 1024;    // 128
    float* p2s = smem + 1152;    // 4*64
    float* y2  = smem + 1408;    // 64
    const int b = blockIdx.x;
    const float* h1T = A.comb1 + (size_t)16 * (1024 * 32) + 512 * 32;
    hv[tid] = h1T[tid * 32 + b];
    __syncthreads();
    {
      int o = tid & 127, seg = tid >> 7;        // 4 segs x 128 k
      float s = 0.f;
      const float* w = A.cw1 + (size_t)(seg * 128) * 128 + o;
      const float* h = hv + seg * 128;
      for (int k = 0; k < 128; ++k) s += h[k] * w[k * 128];
      p1s[seg * 128 + o] = s;
    }
    __syncthreads();
    if (tid < 128)
      y1[tid] = fmaxf(A.cb1[tid] + ((p1s[tid] + p1s[128 + tid]) +
                                    (p1s[256 + tid] + p1s[384 + tid])), 0.f);
    __syncthreads();
    if (tid < 256) {
      int o = tid & 63, seg = tid >> 6;         // 4 segs x 32 k
      float s = 0.f;
      const float* w = A.cw2 + (size_t)(seg * 32) * 64 + o;
      const float* yy = y1 + seg * 32;
      for (int k = 0; k < 32; ++k) s += yy[k] * w[k * 64];
      p2s[seg * 64 + o] = s;
    }
    __syncthreads();
    if (tid < 64)
      y2[tid] = fmaxf(A.cb2[tid] + ((p2s[tid] + p2s[64 + tid]) +
                                    (p2s[128 + tid] + p2s[192 + tid])), 0.f);
    __syncthreads();
    if (tid < 6) {
      float s3 = A.cb3[tid];
      for (int k = 0; k < 64; ++k) s3 += y2[k] * A.cw3[k * 6 + tid];
      A.out[b * 6 + tid] = s3;
    }
  }
}

// ---------------------------------------------------------------------------
// Fallback LSTM (round-9 proven): used only if coop launch is rejected.
struct SArgs {
  const float* comb; const float* pw;
  float* houtA; float* houtB; float* cT;
  const float* bf; const float* bi; const float* bg; const float* bo;
};

template <int FAN>
__device__ __forceinline__ void lstm_sbody(int h, int tid, const SArgs& A,
                                           float* __restrict__ gsum) {
  constexpr int CH = FAN / 8;
  const int wv = __builtin_amdgcn_readfirstlane(tid >> 6);
  const int lane = tid & 63;
  const int ks = lane >> 5, b = lane & 31;
  const int kb = wv * CH;
  const float4* pw4 = (const float4*)A.pw + (size_t)h * FAN + kb;
  const float* ac = A.comb + (size_t)kb * 32 + lane;
  float a0 = 0.f, a1 = 0.f, a2 = 0.f, a3 = 0.f;
#pragma unroll 8
  for (int kk = 0; kk < CH; kk += 2) {
    float4 w0 = pw4[kk];
    float4 w1 = pw4[kk + 1];
    float av = ac[kk * 32];
    a0 += av * (ks ? w1.x : w0.x);
    a1 += av * (ks ? w1.y : w0.y);
    a2 += av * (ks ? w1.z : w0.z);
    a3 += av * (ks ? w1.w : w0.w);
  }
  a0 += __shfl_xor(a0, 32);
  a1 += __shfl_xor(a1, 32);
  a2 += __shfl_xor(a2, 32);
  a3 += __shfl_xor(a3, 32);
  if (lane < 32) {
    gsum[(wv * 4 + 0) * 33 + b] = a0;
    gsum[(wv * 4 + 1) * 33 + b] = a1;
    gsum[(wv * 4 + 2) * 33 + b] = a2;
    gsum[(wv * 4 + 3) * 33 + b] = a3;
  }
  __syncthreads();
  if (tid < 32) {
    float fp = A.bf[h], ip = A.bi[h], gp = A.bg[h], op = A.bo[h];
#pragma unroll
    for (int q = 0; q < 8; ++q) {
      fp += gsum[(q * 4 + 0) * 33 + tid];
      ip += gsum[(q * 4 + 1) * 33 + tid];
      gp += gsum[(q * 4 + 2) * 33 + tid];
      op += gsum[(q * 4 + 3) * 33 + tid];
    }
    float ft = 1.f / (1.f + expf(-fp));
    float it_ = 1.f / (1.f + expf(-ip));
    float gt = tanhf(gp);
    float ot = 1.f / (1.f + expf(-op));
    float cn = ft * A.cT[h * 32 + tid] + it_ * gt;
    A.cT[h * 32 + tid] = cn;
    float hn = ot * tanhf(cn);
    A.houtA[h * 32 + tid] = hn;
    A.houtB[h * 32 + tid] = hn;
  }
}

__global__ __launch_bounds__(512) void k_lstm_s0(SArgs a) {
  __shared__ float gsum[32 * 33];
  lstm_sbody<768>(blockIdx.x, threadIdx.x, a, gsum);
}
__global__ __launch_bounds__(512) void k_lstm_s1(SArgs a) {
  __shared__ float gsum[32 * 33];
  lstm_sbody<1024>(blockIdx.x, threadIdx.x, a, gsum);
}
__global__ __launch_bounds__(512) void k_lstm_spair(SArgs a0, SArgs a1) {
  __shared__ float gsum[32 * 33];
  if (blockIdx.x < 512)
    lstm_sbody<768>(blockIdx.x, threadIdx.x, a0, gsum);
  else
    lstm_sbody<1024>(blockIdx.x - 512, threadIdx.x, a1, gsum);
}

// ---------------------------------------------------------------------------
// classifier (fallback path only; coop path runs it in-kernel)
__global__ void k_cls(const float* __restrict__ h1T, const float* __restrict__ cw1,
                      const float* __restrict__ cb1, const float* __restrict__ cw2,
                      const float* __restrict__ cb2, const float* __restrict__ cw3,
                      const float* __restrict__ cb3, float* __restrict__ out) {
  __shared__ float hv[512];
  __shared__ float y1[128];
  __shared__ float y2[64];
  int b = blockIdx.x, tid = threadIdx.x;
  for (int i = tid; i < 512; i += 128) hv[i] = h1T[i * 32 + b];
  __syncthreads();
  float s = cb1[tid];
  for (int k = 0; k < 512; ++k) s += hv[k] * cw1[k * 128 + tid];
  y1[tid] = fmaxf(s, 0.f);
  __syncthreads();
  if (tid < 64) {
    float s2 = cb2[tid];
    for (int k = 0; k < 128; ++k) s2 += y1[k] * cw2[k * 64 + tid];
    y2[tid] = fmaxf(s2, 0.f);
  }
  __syncthreads();
  if (tid < 6) {
    float s3 = cb3[tid];
    for (int k = 0; k < 64; ++k) s3 += y2[k] * cw3[k * 6 + tid];
    out[b * 6 + tid] = s3;
  }
}

// ---------------------------------------------------------------------------
// Workspace (floats):
//  region0 [0..8,388,608) = a1 (dead after conv2); then reused:
//    p0    @ 0          [1,572,864]  packed l0 weights [512][768][4]
//    p1    @ 1,572,864  [2,097,152]  packed l1 weights [512][1024][4]
//    comb0 @ 3,670,016  [417,792]   comb0[t] = [emb(t), h0(t-1)]
//    comb1 @ 4,087,808  [557,056]   comb1[t] = [h0(t), h1(t-1)]
//    c0,c1 @ 4,644,864  [2*16,384]  (fallback only)
//    bar   @ 4,677,632  [512 ints]  tree-barrier counters (zeroed per call)
//  a2  @ 8,388,608  [4,194,304];  w2t @ 12,582,912;  w3t @ 12,587,520
// Launches: k_conv1p, k_conv2, k_c3p, coop2  (4 total)
extern "C" void kernel_launch(void* const* d_in, const int* in_sizes, int n_in,
                              void* d_out, int out_size, void* d_ws, size_t ws_size,
                              hipStream_t stream) {
  const float* x  = (const float*)d_in[0];
  const float* w1 = (const float*)d_in[1];
  const float* b1 = (const float*)d_in[2];
  const float* w2 = (const float*)d_in[3];
  const float* b2 = (const float*)d_in[4];
  const float* w3 = (const float*)d_in[5];
  const float* b3 = (const float*)d_in[6];
  const float* cw1 = (const float*)d_in[23];
  const float* cb1 = (const float*)d_in[24];
  const float* cw2 = (const float*)d_in[25];
  const float* cb2 = (const float*)d_in[26];
  const float* cw3 = (const float*)d_in[27];
  const float* cb3 = (const float*)d_in[28];

  float* ws = (float*)d_ws;
  float* a1    = ws;
  float* p0    = ws;
  float* p1    = ws + 1572864;
  float* comb0 = ws + 3670016;
  float* comb1 = ws + 4087808;
  float* c0    = ws + 4644864;
  float* c1    = ws + 4661248;
  int*   bar   = (int*)(ws + 4677632);
  float* a2    = ws + 8388608;
  float* w2t   = ws + 12582912;
  float* w3t   = ws + 12587520;
  const int C0 = 768 * 32, C1 = 1024 * 32;

  k_conv1p<<<33056, 256, 0, stream>>>(x, w1, b1, a1, w2, w2t, w3, w3t);
  k_conv2<<<dim3(512, 2), 256, 0, stream>>>(a1, w2t, b2, a2);
  // a1 now dead; everything below may write region0

  C3PArgs cp;
  cp.a2 = a2; cp.w3t = w3t; cp.b3 = b3; cp.comb0 = comb0;
  cp.l00 = (const float*)d_in[7];  cp.l01 = (const float*)d_in[9];
  cp.l02 = (const float*)d_in[11]; cp.l03 = (const float*)d_in[13];
  cp.l10 = (const float*)d_in[15]; cp.l11 = (const float*)d_in[17];
  cp.l12 = (const float*)d_in[19]; cp.l13 = (const float*)d_in[21];
  cp.p0 = p0; cp.p1 = p1;
  cp.c0h = comb0 + 256 * 32; cp.c1h = comb1 + 512 * 32;
  cp.cc = c0; cp.bar = bar;
  k_c3p<<<5120, 256, 0, stream>>>(cp);

  Coop2Args ca;
  ca.comb0 = comb0; ca.comb1 = comb1;
  ca.p0 = p0; ca.p1 = p1;
  ca.b00 = (const float*)d_in[8];  ca.b01 = (const float*)d_in[10];
  ca.b02 = (const float*)d_in[12]; ca.b03 = (const float*)d_in[14];
  ca.b10 = (const float*)d_in[16]; ca.b11 = (const float*)d_in[18];
  ca.b12 = (const float*)d_in[20]; ca.b13 = (const float*)d_in[22];
  ca.bar = bar;
  ca.cw1 = cw1; ca.cb1 = cb1; ca.cw2 = cw2; ca.cb2 = cb2;
  ca.cw3 = cw3; ca.cb3 = cb3; ca.out = (float*)d_out;
  void* kargs[] = {&ca};
  hipError_t cerr = hipLaunchCooperativeKernel(
      (void*)k_lstm_coop2, dim3(256), dim3(512), kargs, COOP2_LDS_BYTES, stream);

  if (cerr != hipSuccess) {
    auto L0 = [&](int t) {
      SArgs a;
      a.comb = comb0 + (size_t)t * C0;
      a.pw = p0;
      a.houtA = comb0 + (size_t)(t + 1) * C0 + 256 * 32;
      a.houtB = comb1 + (size_t)t * C1;
      a.cT = c0;
      a.bf = (const float*)d_in[8];  a.bi = (const float*)d_in[10];
      a.bg = (const float*)d_in[12]; a.bo = (const float*)d_in[14];
      return a;
    };
    auto L1 = [&](int t) {
      SArgs a;
      a.comb = comb1 + (size_t)t * C1;
      a.pw = p1;
      a.houtA = comb1 + (size_t)(t + 1) * C1 + 512 * 32;
      a.houtB = a.houtA;
      a.cT = c1;
      a.bf = (const float*)d_in[16]; a.bi = (const float*)d_in[18];
      a.bg = (const float*)d_in[20]; a.bo = (const float*)d_in[22];
      return a;
    };
    k_lstm_s0<<<512, 512, 0, stream>>>(L0(0));
    for (int p = 0; p < 15; ++p)
      k_lstm_spair<<<1024, 512, 0, stream>>>(L0(p + 1), L1(p));
    k_lstm_s1<<<512, 512, 0, stream>>>(L1(15));
    k_cls<<<32, 128, 0, stream>>>(comb1 + (size_t)16 * C1 + 512 * 32,
                                  cw1, cb1, cw2, cb2, cw3, cb3, (float*)d_out);
  }
}

// Round 23
// 575.296 us; speedup vs baseline: 1.2320x; 1.2320x over previous
//
#include <hip/hip_runtime.h>
#include <math.h>

// ---------------------------------------------------------------------------
// conv1 + prep_w fused (both independent, both must precede conv2).
__global__ void k_conv1p(const float* __restrict__ x, const float* __restrict__ w1,
                         const float* __restrict__ b1, float* __restrict__ a1,
                         const float* __restrict__ w2, float* __restrict__ w2t,
                         const float* __restrict__ w3, float* __restrict__ w3t) {
  if (blockIdx.x < 32768) {
    int idx = blockIdx.x * 256 + threadIdx.x;
    int ox = idx & 31, oy = (idx >> 5) & 31, oc = (idx >> 10) & 15, n = idx >> 14;
    const float* im = x + n * 4096;
    float wv[9];
#pragma unroll
    for (int i = 0; i < 9; ++i) wv[i] = w1[oc * 9 + i];
    float bs = b1[oc];
    float m = 0.f;
#pragma unroll
    for (int dy = 0; dy < 2; ++dy)
#pragma unroll
      for (int dx = 0; dx < 2; ++dx) {
        int cy = oy * 2 + dy, cx = ox * 2 + dx;
        float s = bs;
#pragma unroll
        for (int ky = 0; ky < 3; ++ky) {
          int yy = cy + ky - 1;
          if (yy < 0 || yy >= 64) continue;
#pragma unroll
          for (int kx = 0; kx < 3; ++kx) {
            int xx = cx + kx - 1;
            if (xx < 0 || xx >= 64) continue;
            s += im[yy * 64 + xx] * wv[ky * 3 + kx];
          }
        }
        m = fmaxf(m, fmaxf(s, 0.f));
      }
    a1[idx] = m;
  } else {
    int id = (blockIdx.x - 32768) * 256 + threadIdx.x;
    if (id < 73728) {
      int ct = id >> 8, oc = id & 255;
      int c = ct / 9, tap = ct - 9 * c;
      w3t[id] = w3[(oc * 32 + c) * 9 + tap];
    }
    if (id < 4608) {
      int ct = id >> 5, oc = id & 31;
      int c = ct / 9, tap = ct - 9 * c;
      w2t[id] = w2[(oc * 16 + c) * 9 + tap];
    }
  }
}

// ---------------------------------------------------------------------------
// zero + pack(p0) + pack(p1) fused (all must follow conv2: region0 aliasing).
struct Prep2Args {
  const float* l00; const float* l01; const float* l02; const float* l03;
  const float* l10; const float* l11; const float* l12; const float* l13;
  float* p0; float* p1;
  float* c0h; float* c1h; float* cc; int* bar;
};

__device__ __forceinline__ void pack_body(
    const float* __restrict__ Wf, const float* __restrict__ Wi,
    const float* __restrict__ Wg, const float* __restrict__ Wo,
    float* __restrict__ p, int fan, int k0, int h0, int tid,
    float* __restrict__ t) {  // t = [4][32][33] floats
  int tx = tid & 31, ty = tid >> 5;  // 32 x 8
  const float* Ws[4] = {Wf, Wi, Wg, Wo};
#pragma unroll
  for (int g = 0; g < 4; ++g)
    for (int r = 0; r < 32; r += 8)
      t[(g * 32 + ty + r) * 33 + tx] =
          Ws[g][(size_t)(k0 + ty + r) * 512 + h0 + tx];
  __syncthreads();
  for (int r = 0; r < 32; r += 8) {
    int hh = ty + r;
    float4 v = {t[(0 * 32 + tx) * 33 + hh], t[(1 * 32 + tx) * 33 + hh],
                t[(2 * 32 + tx) * 33 + hh], t[(3 * 32 + tx) * 33 + hh]};
    ((float4*)p)[(size_t)(h0 + hh) * fan + k0 + tx] = v;
  }
}

__global__ void k_prep2(Prep2Args P) {
  __shared__ float t[4 * 32 * 33];
  int bid = blockIdx.x, tid = threadIdx.x;
  if (bid < 384) {
    pack_body(P.l00, P.l01, P.l02, P.l03, P.p0, 768,
              (bid % 24) * 32, (bid / 24) * 32, tid, t);
  } else if (bid < 896) {
    int b2 = bid - 384;
    pack_body(P.l10, P.l11, P.l12, P.l13, P.p1, 1024,
              (b2 % 32) * 32, (b2 / 32) * 32, tid, t);
  } else {
    int i = (bid - 896) * 256 + tid;  // [0, 32768)
    if (i < 16384) { P.c0h[i] = 0.f; P.c1h[i] = 0.f; }
    P.cc[i] = 0.f;
    if (i < 512) P.bar[i] = 0;
  }
}

// ---------------------------------------------------------------------------
// conv2: a1[512][16][32][32] -> relu -> maxpool2 -> a2[n][px=256][oc=32]
__global__ __launch_bounds__(256) void k_conv2(
    const float* __restrict__ a1, const float* __restrict__ w2t,
    const float* __restrict__ bias, float* __restrict__ a2) {
  __shared__ __align__(16) float ins[8 * 1024];
  int n = blockIdx.x, ocg = blockIdx.y;
  int tid = threadIdx.x;
  int py = tid >> 4, px = tid & 15;
  int y0 = 2 * py - 1, x0 = 2 * px - 1;
  float acc[16][4] = {};
  const float* wb = w2t + ocg * 16;
  for (int ph = 0; ph < 2; ++ph) {
    __syncthreads();
    const float4* src = (const float4*)(a1 + n * 16384 + ph * 8192);
    for (int i = tid; i < 2048; i += 256) ((float4*)ins)[i] = src[i];
    __syncthreads();
    for (int c = 0; c < 8; ++c) {
      float wv[4][4];
#pragma unroll
      for (int r = 0; r < 4; ++r) {
        int y = y0 + r;
        bool vy = (y >= 0) && (y < 32);
        int yc = vy ? y : 0;
#pragma unroll
        for (int cc = 0; cc < 4; ++cc) {
          int xx = x0 + cc;
          bool vx = (xx >= 0) && (xx < 32);
          int xc = vx ? xx : 0;
          float t = ins[c * 1024 + yc * 32 + xc];
          wv[r][cc] = (vy && vx) ? t : 0.f;
        }
      }
      int ch = ph * 8 + c;
#pragma unroll
      for (int ky = 0; ky < 3; ++ky)
#pragma unroll
        for (int kx = 0; kx < 3; ++kx) {
          const float* w16 = wb + (ch * 9 + ky * 3 + kx) * 32;
#pragma unroll
          for (int i = 0; i < 4; ++i) {
            float vv = wv[(i >> 1) + ky][(i & 1) + kx];
#pragma unroll
            for (int j = 0; j < 16; ++j) acc[j][i] += vv * w16[j];
          }
        }
    }
  }
  const float* bp = bias + ocg * 16;
  float4 o[4];
#pragma unroll
  for (int j = 0; j < 16; ++j) {
    float m = fmaxf(fmaxf(acc[j][0], acc[j][1]), fmaxf(acc[j][2], acc[j][3]));
    ((float*)o)[j] = fmaxf(m + bp[j], 0.f);
  }
  float4* dst = (float4*)(a2 + (size_t)(n * 256 + tid) * 32 + ocg * 16);
#pragma unroll
  for (int q = 0; q < 4; ++q) dst[q] = o[q];
}

// ---------------------------------------------------------------------------
// conv3 v7 (best measured ~195us; v3/v7 = measured local optimum; round-22
// showed even wrapping this body in a fused dispatch regresses it 60% --
// keep the exact standalone kernel form)
__global__ __launch_bounds__(256) void k_conv3(
    const float* __restrict__ a2, const float* __restrict__ w3t,
    const float* __restrict__ bias, float* __restrict__ comb0) {
  __shared__ __align__(16) float ins[324 * 10];  // 12,960 B: [324 px][5 f2]
  float2* ins2 = (float2*)ins;
  int n = blockIdx.x, ocb = blockIdx.y;
  int tid = threadIdx.x;
  for (int i = tid; i < 810; i += 256) ((float4*)ins)[i] = float4{0.f, 0.f, 0.f, 0.f};
  int wvid = __builtin_amdgcn_readfirstlane(tid >> 6);
  int lane = tid & 63;
  int tr = lane >> 4, tc = lane & 15;
  float acc[4][8] = {};
  const float* wbase = w3t + ocb * 32 + wvid * 8;
  const float4* src = (const float4*)(a2 + (size_t)n * 8192);
  for (int ph = 0; ph < 4; ++ph) {
    __syncthreads();
    for (int i = tid; i < 512; i += 256) {
      int px = i >> 1, cgl = i & 1;
      int p = ((px >> 4) + 1) * 18 + (px & 15) + 1;
      float4 v = src[px * 8 + ph * 2 + cgl];
      ins2[p * 5 + cgl * 2]     = float2{v.x, v.y};
      ins2[p * 5 + cgl * 2 + 1] = float2{v.z, v.w};
    }
    __syncthreads();
    for (int cg2 = 0; cg2 < 4; ++cg2) {
      float2 v[6][3];
#pragma unroll
      for (int dr = 0; dr < 6; ++dr)
#pragma unroll
        for (int dc = 0; dc < 3; ++dc)
          v[dr][dc] = ins2[((4 * tr + dr) * 18 + tc + dc) * 5 + cg2];
#pragma unroll
      for (int ky = 0; ky < 3; ++ky)
#pragma unroll
        for (int kx = 0; kx < 3; ++kx)
#pragma unroll
          for (int c = 0; c < 2; ++c) {
            const float* w8 =
                wbase + ((ph * 8 + cg2 * 2 + c) * 9 + ky * 3 + kx) * 256;
#pragma unroll
            for (int i = 0; i < 4; ++i) {
              float vv = c ? v[i + ky][kx].y : v[i + ky][kx].x;
#pragma unroll
              for (int j = 0; j < 8; ++j) acc[i][j] += vv * w8[j];
            }
          }
    }
  }
  const float* bp = bias + ocb * 32 + wvid * 8;
  int bb = n >> 4, tt = n & 15;
#pragma unroll
  for (int j = 0; j < 8; ++j) {
    float bj = bp[j];
    float s = 0.f;
#pragma unroll
    for (int i = 0; i < 4; ++i) s += fmaxf(acc[i][j] + bj, 0.f);
#pragma unroll
    for (int off = 32; off; off >>= 1) s += __shfl_down(s, off, 64);
    if (lane == 0) {
      int oc = ocb * 32 + wvid * 8 + j;
      comb0[(size_t)(tt * 768 + oc) * 32 + bb] = s * (1.f / 256.f);
    }
  }
}

// ---------------------------------------------------------------------------
// Persistent cooperative LSTM v15 + parallel classifier tail (round-21
// passing, ~233us). Hot MAC loops byte-identical.
struct Coop2Args {
  float* comb0; float* comb1;
  const float* p0; const float* p1;   // packed [512][FAN][4]
  const float* b00; const float* b01; const float* b02; const float* b03;
  const float* b10; const float* b11; const float* b12; const float* b13;
  int* bar;   // [512] ints: root @0; group g counter @ 32+g*32
  const float* cw1; const float* cb1; const float* cw2; const float* cb2;
  const float* cw3; const float* cb3; float* out;
};

// LDS floats: wl0 [0,6144) | wl1 [6144,14336) | gsum [14336,31488) |
// pre0 [31488,32000) | pre1 [32000,32512)  => 130,048 B (1 blk/CU)
#define COOP2_LDS_BYTES (32512 * 4)

#define FMA4(acc, s, a)                                   \
  acc.x += (s) * (a).x; acc.y += (s) * (a).y;             \
  acc.z += (s) * (a).z; acc.w += (s) * (a).w;

template <bool DO0, bool DO1>
__device__ __forceinline__ void fused_step(
    int hbase, int tid, int it, const Coop2Args& A,
    const float4* __restrict__ w40, const float4* __restrict__ w41,
    float* __restrict__ gsum, float* __restrict__ pre0,
    float* __restrict__ pre1,
    float bf0, float bi0, float bg0, float bo0,
    float bf1, float bi1, float bg1, float bo1,
    float& c0reg, float& c1reg) {
  const int C0 = 768 * 32, C1 = 1024 * 32;
  const int kc = tid >> 3, bq = tid & 7;
  float4 p0f{0,0,0,0}, p0i{0,0,0,0}, p0g{0,0,0,0}, p0o{0,0,0,0};
  float4 p1f{0,0,0,0}, p1i{0,0,0,0}, p1g{0,0,0,0}, p1o{0,0,0,0};
  float4 q0f{0,0,0,0}, q0i{0,0,0,0}, q0g{0,0,0,0}, q0o{0,0,0,0};
  float4 q1f{0,0,0,0}, q1i{0,0,0,0}, q1g{0,0,0,0}, q1o{0,0,0,0};
  if constexpr (DO1) {
    const float4* a41 = (const float4*)(A.comb1 + (size_t)(it - 1) * C1)
                        + kc * 8 + bq;
#pragma unroll
    for (int kk = 0; kk < 16; ++kk) {
      float4 a = a41[kk * 512];
      float4 u = w41[kk * 64];           // hs0 gates f,i,g,o for k=kk*64+kc
      float4 v = w41[1024 + kk * 64];    // hs1
      FMA4(q0f, u.x, a) FMA4(q0i, u.y, a) FMA4(q0g, u.z, a) FMA4(q0o, u.w, a)
      FMA4(q1f, v.x, a) FMA4(q1i, v.y, a) FMA4(q1g, v.z, a) FMA4(q1o, v.w, a)
    }
  }
  if constexpr (DO0) {
    const float4* a40 = (const float4*)(A.comb0 + (size_t)it * C0)
                        + kc * 8 + bq;
#pragma unroll
    for (int kk = 0; kk < 12; ++kk) {
      float4 a = a40[kk * 512];
      float4 u = w40[kk * 64];
      float4 v = w40[768 + kk * 64];
      FMA4(p0f, u.x, a) FMA4(p0i, u.y, a) FMA4(p0g, u.z, a) FMA4(p0o, u.w, a)
      FMA4(p1f, v.x, a) FMA4(p1i, v.y, a) FMA4(p1g, v.z, a) FMA4(p1o, v.w, a)
    }
  }
#define GW(hsv, gv, acc) {                                            \
    float* _r = gsum + (size_t)(((hsv) * 4 + (gv)) * 32 + 4 * bq) * 67 + kc; \
    _r[0] = acc.x; _r[67] = acc.y; _r[134] = acc.z; _r[201] = acc.w; }
  __syncthreads();   // previous consumers of gsum/pre done
  if constexpr (DO0) {
    GW(0, 0, p0f) GW(0, 1, p0i) GW(0, 2, p0g) GW(0, 3, p0o)
    GW(1, 0, p1f) GW(1, 1, p1i) GW(1, 2, p1g) GW(1, 3, p1o)
  }
  __syncthreads();
  if constexpr (DO0) {
    int row = tid & 255, half = tid >> 8;
    const float* gp = gsum + (size_t)row * 67 + half * 32;
    float s = 0.f;
#pragma unroll
    for (int q = 0; q < 32; ++q) s += gp[q];
    pre0[half * 256 + row] = s;
  }
  __syncthreads();   // gsum reads done -> reuse for l1
  if constexpr (DO1) {
    GW(0, 0, q0f) GW(0, 1, q0i) GW(0, 2, q0g) GW(0, 3, q0o)
    GW(1, 0, q1f) GW(1, 1, q1i) GW(1, 2, q1g) GW(1, 3, q1o)
  }
  __syncthreads();
  if constexpr (DO1) {
    int row = tid & 255, half = tid >> 8;
    const float* gp = gsum + (size_t)row * 67 + half * 32;
    float s = 0.f;
#pragma unroll
    for (int q = 0; q < 32; ++q) s += gp[q];
    pre1[half * 256 + row] = s;
  }
  __syncthreads();
#undef GW
  if (tid < 64) {
    int hs2 = tid >> 5, b = tid & 31, hh = hbase + hs2;
    int r = hs2 * 128 + b;
    if constexpr (DO0) {
      float fp = pre0[r] + pre0[256 + r] + bf0;
      float ip = pre0[r + 32] + pre0[256 + r + 32] + bi0;
      float gp = pre0[r + 64] + pre0[256 + r + 64] + bg0;
      float op = pre0[r + 96] + pre0[256 + r + 96] + bo0;
      float ft = 1.f / (1.f + expf(-fp));
      float it_ = 1.f / (1.f + expf(-ip));
      float gt = tanhf(gp);
      float ot = 1.f / (1.f + expf(-op));
      float cn = ft * c0reg + it_ * gt;
      c0reg = cn;
      float hn = ot * tanhf(cn);
      float* hA = A.comb0 + (size_t)(it + 1) * C0 + 256 * 32;
      float* hB = A.comb1 + (size_t)it * C1;
      __hip_atomic_store(&hA[hh * 32 + b], hn, __ATOMIC_RELAXED,
                         __HIP_MEMORY_SCOPE_AGENT);
      __hip_atomic_store(&hB[hh * 32 + b], hn, __ATOMIC_RELAXED,
                         __HIP_MEMORY_SCOPE_AGENT);
    }
    if constexpr (DO1) {
      float fp = pre1[r] + pre1[256 + r] + bf1;
      float ip = pre1[r + 32] + pre1[256 + r + 32] + bi1;
      float gp = pre1[r + 64] + pre1[256 + r + 64] + bg1;
      float op = pre1[r + 96] + pre1[256 + r + 96] + bo1;
      float ft = 1.f / (1.f + expf(-fp));
      float it_ = 1.f / (1.f + expf(-ip));
      float gt = tanhf(gp);
      float ot = 1.f / (1.f + expf(-op));
      float cn = ft * c1reg + it_ * gt;
      c1reg = cn;
      float hn = ot * tanhf(cn);
      float* hA = A.comb1 + (size_t)it * C1 + 512 * 32;
      __hip_atomic_store(&hA[hh * 32 + b], hn, __ATOMIC_RELAXED,
                         __HIP_MEMORY_SCOPE_AGENT);
    }
  }
}

// tree barrier: 8 group counters on separate lines (32 arrivals, ACQ_REL) +
// root (8 arrivals, RELEASE); poll root RELAXED + one ACQUIRE agent fence.
__device__ __forceinline__ void coop_barrier(int* bars, int tid, int bid,
                                             int it) {
  __syncthreads();
  if (tid == 0) {
    int* gb = bars + 32 + (bid & 7) * 32;
    int old = __hip_atomic_fetch_add(gb, 1, __ATOMIC_ACQ_REL,
                                     __HIP_MEMORY_SCOPE_AGENT);
    if (old == 32 * (it + 1) - 1)
      __hip_atomic_fetch_add(bars, 1, __ATOMIC_RELEASE,
                             __HIP_MEMORY_SCOPE_AGENT);
    while (__hip_atomic_load(bars, __ATOMIC_RELAXED,
                             __HIP_MEMORY_SCOPE_AGENT) < 8 * (it + 1))
      __builtin_amdgcn_s_sleep(2);
    __builtin_amdgcn_fence(__ATOMIC_ACQUIRE, "agent");
  }
  __syncthreads();
}

__global__ __launch_bounds__(512, 2) void k_lstm_coop2(Coop2Args A) {
  extern __shared__ float smem[];
  float* wl0 = smem;
  float* wl1 = smem + 6144;
  float* gsum = smem + 14336;
  float* pre0 = smem + 31488;
  float* pre1 = smem + 32000;
  const int tid = threadIdx.x;
  const int hbase = blockIdx.x * 2;
  // stage both layers' weights once
  for (int i = tid; i < 1536; i += 512) {
    int hs = (i >= 768), k = i - hs * 768;
    ((float4*)wl0)[hs * 768 + k] =
        ((const float4*)A.p0)[(size_t)(hbase + hs) * 768 + k];
  }
  for (int i = tid; i < 2048; i += 512) {
    int hs = i >> 10, k = i & 1023;
    ((float4*)wl1)[hs * 1024 + k] =
        ((const float4*)A.p1)[(size_t)(hbase + hs) * 1024 + k];
  }
  float bf0 = 0, bi0 = 0, bg0 = 0, bo0 = 0;
  float bf1 = 0, bi1 = 0, bg1 = 0, bo1 = 0;
  float c0reg = 0.f, c1reg = 0.f;
  if (tid < 64) {
    int hh = hbase + (tid >> 5);
    bf0 = A.b00[hh]; bi0 = A.b01[hh]; bg0 = A.b02[hh]; bo0 = A.b03[hh];
    bf1 = A.b10[hh]; bi1 = A.b11[hh]; bg1 = A.b12[hh]; bo1 = A.b13[hh];
  }
  __syncthreads();
  const int kc = tid >> 3;
  const float4* w40 = (const float4*)wl0 + kc;
  const float4* w41 = (const float4*)wl1 + kc;

  fused_step<true, false>(hbase, tid, 0, A, w40, w41, gsum, pre0, pre1,
                          bf0, bi0, bg0, bo0, bf1, bi1, bg1, bo1, c0reg, c1reg);
  coop_barrier(A.bar, tid, blockIdx.x, 0);
  for (int it = 1; it < 16; ++it) {
    fused_step<true, true>(hbase, tid, it, A, w40, w41, gsum, pre0, pre1,
                           bf0, bi0, bg0, bo0, bf1, bi1, bg1, bo1, c0reg, c1reg);
    coop_barrier(A.bar, tid, blockIdx.x, it);
  }
  fused_step<false, true>(hbase, tid, 16, A, w40, w41, gsum, pre0, pre1,
                          bf0, bi0, bg0, bo0, bf1, bi1, bg1, bo1, c0reg, c1reg);

  // final barrier: ALL blocks arrive; only cls blocks (0..31) poll.
  __syncthreads();
  if (tid == 0) {
    int* gb = A.bar + 32 + (blockIdx.x & 7) * 32;
    int old = __hip_atomic_fetch_add(gb, 1, __ATOMIC_ACQ_REL,
                                     __HIP_MEMORY_SCOPE_AGENT);
    if (old == 32 * 17 - 1)
      __hip_atomic_fetch_add(A.bar, 1, __ATOMIC_RELEASE,
                             __HIP_MEMORY_SCOPE_AGENT);
  }
  if (blockIdx.x < 32) {
    if (tid == 0) {
      while (__hip_atomic_load(A.bar, __ATOMIC_RELAXED,
                               __HIP_MEMORY_SCOPE_AGENT) < 8 * 17)
        __builtin_amdgcn_s_sleep(2);
      __builtin_amdgcn_fence(__ATOMIC_ACQUIRE, "agent");
    }
    __syncthreads();
    // parallel classifier for batch b = blockIdx.x (split-k via LDS)
    float* hv  = smem;           // 512   (wl0 region, dead)
    float* p1s = smem + 512;     // 4*128
    float* y1  = smem + 1024;    // 128
    float* p2s = smem + 1152;    // 4*64
    float* y2  = smem + 1408;    // 64
    const int b = blockIdx.x;
    const float* h1T = A.comb1 + (size_t)16 * (1024 * 32) + 512 * 32;
    hv[tid] = h1T[tid * 32 + b];
    __syncthreads();
    {
      int o = tid & 127, seg = tid >> 7;        // 4 segs x 128 k
      float s = 0.f;
      const float* w = A.cw1 + (size_t)(seg * 128) * 128 + o;
      const float* h = hv + seg * 128;
      for (int k = 0; k < 128; ++k) s += h[k] * w[k * 128];
      p1s[seg * 128 + o] = s;
    }
    __syncthreads();
    if (tid < 128)
      y1[tid] = fmaxf(A.cb1[tid] + ((p1s[tid] + p1s[128 + tid]) +
                                    (p1s[256 + tid] + p1s[384 + tid])), 0.f);
    __syncthreads();
    if (tid < 256) {
      int o = tid & 63, seg = tid >> 6;         // 4 segs x 32 k
      float s = 0.f;
      const float* w = A.cw2 + (size_t)(seg * 32) * 64 + o;
      const float* yy = y1 + seg * 32;
      for (int k = 0; k < 32; ++k) s += yy[k] * w[k * 64];
      p2s[seg * 64 + o] = s;
    }
    __syncthreads();
    if (tid < 64)
      y2[tid] = fmaxf(A.cb2[tid] + ((p2s[tid] + p2s[64 + tid]) +
                                    (p2s[128 + tid] + p2s[192 + tid])), 0.f);
    __syncthreads();
    if (tid < 6) {
      float s3 = A.cb3[tid];
      for (int k = 0; k < 64; ++k) s3 += y2[k] * A.cw3[k * 6 + tid];
      A.out[b * 6 + tid] = s3;
    }
  }
}

// ---------------------------------------------------------------------------
// Fallback LSTM (round-9 proven): used only if coop launch is rejected.
struct SArgs {
  const float* comb; const float* pw;
  float* houtA; float* houtB; float* cT;
  const float* bf; const float* bi; const float* bg; const float* bo;
};

template <int FAN>
__device__ __forceinline__ void lstm_sbody(int h, int tid, const SArgs& A,
                                           float* __restrict__ gsum) {
  constexpr int CH = FAN / 8;
  const int wv = __builtin_amdgcn_readfirstlane(tid >> 6);
  const int lane = tid & 63;
  const int ks = lane >> 5, b = lane & 31;
  const int kb = wv * CH;
  const float4* pw4 = (const float4*)A.pw + (size_t)h * FAN + kb;
  const float* ac = A.comb + (size_t)kb * 32 + lane;
  float a0 = 0.f, a1 = 0.f, a2 = 0.f, a3 = 0.f;
#pragma unroll 8
  for (int kk = 0; kk < CH; kk += 2) {
    float4 w0 = pw4[kk];
    float4 w1 = pw4[kk + 1];
    float av = ac[kk * 32];
    a0 += av * (ks ? w1.x : w0.x);
    a1 += av * (ks ? w1.y : w0.y);
    a2 += av * (ks ? w1.z : w0.z);
    a3 += av * (ks ? w1.w : w0.w);
  }
  a0 += __shfl_xor(a0, 32);
  a1 += __shfl_xor(a1, 32);
  a2 += __shfl_xor(a2, 32);
  a3 += __shfl_xor(a3, 32);
  if (lane < 32) {
    gsum[(wv * 4 + 0) * 33 + b] = a0;
    gsum[(wv * 4 + 1) * 33 + b] = a1;
    gsum[(wv * 4 + 2) * 33 + b] = a2;
    gsum[(wv * 4 + 3) * 33 + b] = a3;
  }
  __syncthreads();
  if (tid < 32) {
    float fp = A.bf[h], ip = A.bi[h], gp = A.bg[h], op = A.bo[h];
#pragma unroll
    for (int q = 0; q < 8; ++q) {
      fp += gsum[(q * 4 + 0) * 33 + tid];
      ip += gsum[(q * 4 + 1) * 33 + tid];
      gp += gsum[(q * 4 + 2) * 33 + tid];
      op += gsum[(q * 4 + 3) * 33 + tid];
    }
    float ft = 1.f / (1.f + expf(-fp));
    float it_ = 1.f / (1.f + expf(-ip));
    float gt = tanhf(gp);
    float ot = 1.f / (1.f + expf(-op));
    float cn = ft * A.cT[h * 32 + tid] + it_ * gt;
    A.cT[h * 32 + tid] = cn;
    float hn = ot * tanhf(cn);
    A.houtA[h * 32 + tid] = hn;
    A.houtB[h * 32 + tid] = hn;
  }
}

__global__ __launch_bounds__(512) void k_lstm_s0(SArgs a) {
  __shared__ float gsum[32 * 33];
  lstm_sbody<768>(blockIdx.x, threadIdx.x, a, gsum);
}
__global__ __launch_bounds__(512) void k_lstm_s1(SArgs a) {
  __shared__ float gsum[32 * 33];
  lstm_sbody<1024>(blockIdx.x, threadIdx.x, a, gsum);
}
__global__ __launch_bounds__(512) void k_lstm_spair(SArgs a0, SArgs a1) {
  __shared__ float gsum[32 * 33];
  if (blockIdx.x < 512)
    lstm_sbody<768>(blockIdx.x, threadIdx.x, a0, gsum);
  else
    lstm_sbody<1024>(blockIdx.x - 512, threadIdx.x, a1, gsum);
}

// ---------------------------------------------------------------------------
// classifier (fallback path only; coop path runs it in-kernel)
__global__ void k_cls(const float* __restrict__ h1T, const float* __restrict__ cw1,
                      const float* __restrict__ cb1, const float* __restrict__ cw2,
                      const float* __restrict__ cb2, const float* __restrict__ cw3,
                      const float* __restrict__ cb3, float* __restrict__ out) {
  __shared__ float hv[512];
  __shared__ float y1[128];
  __shared__ float y2[64];
  int b = blockIdx.x, tid = threadIdx.x;
  for (int i = tid; i < 512; i += 128) hv[i] = h1T[i * 32 + b];
  __syncthreads();
  float s = cb1[tid];
  for (int k = 0; k < 512; ++k) s += hv[k] * cw1[k * 128 + tid];
  y1[tid] = fmaxf(s, 0.f);
  __syncthreads();
  if (tid < 64) {
    float s2 = cb2[tid];
    for (int k = 0; k < 128; ++k) s2 += y1[k] * cw2[k * 64 + tid];
    y2[tid] = fmaxf(s2, 0.f);
  }
  __syncthreads();
  if (tid < 6) {
    float s3 = cb3[tid];
    for (int k = 0; k < 64; ++k) s3 += y2[k] * cw3[k * 6 + tid];
    out[b * 6 + tid] = s3;
  }
}

// ---------------------------------------------------------------------------
// Workspace (floats):
//  region0 [0..8,388,608) = a1 (dead after conv2); then reused:
//    p0    @ 0          [1,572,864]  packed l0 weights [512][768][4]
//    p1    @ 1,572,864  [2,097,152]  packed l1 weights [512][1024][4]
//    comb0 @ 3,670,016  [417,792]   comb0[t] = [emb(t), h0(t-1)]
//    comb1 @ 4,087,808  [557,056]   comb1[t] = [h0(t), h1(t-1)]
//    c0,c1 @ 4,644,864  [2*16,384]  (fallback only)
//    bar   @ 4,677,632  [512 ints]  tree-barrier counters (zeroed per call)
//  a2  @ 8,388,608  [4,194,304];  w2t @ 12,582,912;  w3t @ 12,587,520
// Launches: k_conv1p, k_conv2, k_prep2, k_conv3, coop2  (round-21 config,
// best measured 577.9us; round-22's conv3+prep fusion regressed 60% and
// was reverted)
extern "C" void kernel_launch(void* const* d_in, const int* in_sizes, int n_in,
                              void* d_out, int out_size, void* d_ws, size_t ws_size,
                              hipStream_t stream) {
  const float* x  = (const float*)d_in[0];
  const float* w1 = (const float*)d_in[1];
  const float* b1 = (const float*)d_in[2];
  const float* w2 = (const float*)d_in[3];
  const float* b2 = (const float*)d_in[4];
  const float* w3 = (const float*)d_in[5];
  const float* b3 = (const float*)d_in[6];
  const float* cw1 = (const float*)d_in[23];
  const float* cb1 = (const float*)d_in[24];
  const float* cw2 = (const float*)d_in[25];
  const float* cb2 = (const float*)d_in[26];
  const float* cw3 = (const float*)d_in[27];
  const float* cb3 = (const float*)d_in[28];

  float* ws = (float*)d_ws;
  float* a1    = ws;
  float* p0    = ws;
  float* p1    = ws + 1572864;
  float* comb0 = ws + 3670016;
  float* comb1 = ws + 4087808;
  float* c0    = ws + 4644864;
  float* c1    = ws + 4661248;
  int*   bar   = (int*)(ws + 4677632);
  float* a2    = ws + 8388608;
  float* w2t   = ws + 12582912;
  float* w3t   = ws + 12587520;
  const int C0 = 768 * 32, C1 = 1024 * 32;

  k_conv1p<<<33056, 256, 0, stream>>>(x, w1, b1, a1, w2, w2t, w3, w3t);
  k_conv2<<<dim3(512, 2), 256, 0, stream>>>(a1, w2t, b2, a2);
  // a1 now dead; everything below may write region0

  Prep2Args pp;
  pp.l00 = (const float*)d_in[7];  pp.l01 = (const float*)d_in[9];
  pp.l02 = (const float*)d_in[11]; pp.l03 = (const float*)d_in[13];
  pp.l10 = (const float*)d_in[15]; pp.l11 = (const float*)d_in[17];
  pp.l12 = (const float*)d_in[19]; pp.l13 = (const float*)d_in[21];
  pp.p0 = p0; pp.p1 = p1;
  pp.c0h = comb0 + 256 * 32; pp.c1h = comb1 + 512 * 32;
  pp.cc = c0; pp.bar = bar;
  k_prep2<<<1024, 256, 0, stream>>>(pp);

  k_conv3<<<dim3(512, 8), 256, 0, stream>>>(a2, w3t, b3, comb0);

  Coop2Args ca;
  ca.comb0 = comb0; ca.comb1 = comb1;
  ca.p0 = p0; ca.p1 = p1;
  ca.b00 = (const float*)d_in[8];  ca.b01 = (const float*)d_in[10];
  ca.b02 = (const float*)d_in[12]; ca.b03 = (const float*)d_in[14];
  ca.b10 = (const float*)d_in[16]; ca.b11 = (const float*)d_in[18];
  ca.b12 = (const float*)d_in[20]; ca.b13 = (const float*)d_in[22];
  ca.bar = bar;
  ca.cw1 = cw1; ca.cb1 = cb1; ca.cw2 = cw2; ca.cb2 = cb2;
  ca.cw3 = cw3; ca.cb3 = cb3; ca.out = (float*)d_out;
  void* kargs[] = {&ca};
  hipError_t cerr = hipLaunchCooperativeKernel(
      (void*)k_lstm_coop2, dim3(256), dim3(512), kargs, COOP2_LDS_BYTES, stream);

  if (cerr != hipSuccess) {
    auto L0 = [&](int t) {
      SArgs a;
      a.comb = comb0 + (size_t)t * C0;
      a.pw = p0;
      a.houtA = comb0 + (size_t)(t + 1) * C0 + 256 * 32;
      a.houtB = comb1 + (size_t)t * C1;
      a.cT = c0;
      a.bf = (const float*)d_in[8];  a.bi = (const float*)d_in[10];
      a.bg = (const float*)d_in[12]; a.bo = (const float*)d_in[14];
      return a;
    };
    auto L1 = [&](int t) {
      SArgs a;
      a.comb = comb1 + (size_t)t * C1;
      a.pw = p1;
      a.houtA = comb1 + (size_t)(t + 1) * C1 + 512 * 32;
      a.houtB = a.houtA;
      a.cT = c1;
      a.bf = (const float*)d_in[16]; a.bi = (const float*)d_in[18];
      a.bg = (const float*)d_in[20]; a.bo = (const float*)d_in[22];
      return a;
    };
    k_lstm_s0<<<512, 512, 0, stream>>>(L0(0));
    for (int p = 0; p < 15; ++p)
      k_lstm_spair<<<1024, 512, 0, stream>>>(L0(p + 1), L1(p));
    k_lstm_s1<<<512, 512, 0, stream>>>(L1(15));
    k_cls<<<32, 128, 0, stream>>>(comb1 + (size_t)16 * C1 + 512 * 32,
                                  cw1, cb1, cw2, cb2, cw3, cb3, (float*)d_out);
  }
}